// Round 1
// baseline (532.492 us; speedup 1.0000x reference)
//
#include <hip/hip_runtime.h>

// Problem constants (from reference setup_inputs)
#define N_NODES 50000
#define N_EDGES 800000
#define FDIM    64
#define NGRAPH  128

// ---------- kernels ----------

__global__ void k_init_deg(float* __restrict__ deg, int n) {
    int i = blockIdx.x * blockDim.x + threadIdx.x;
    if (i < n) deg[i] = 1.0f;  // self-loop contributes 1
}

__global__ void k_deg_accum(const int* __restrict__ col, float* __restrict__ deg, int e) {
    int i = blockIdx.x * blockDim.x + threadIdx.x;
    if (i < e) atomicAdd(&deg[col[i]], 1.0f);
}

__global__ void k_finish_dinv(float* __restrict__ deg, int n) {
    int i = blockIdx.x * blockDim.x + threadIdx.x;
    if (i < n) deg[i] = rsqrtf(deg[i]);   // deg >= 1 always (self loop)
}

// h = x @ W   (x: [N,64], W: [64,64], h: [N,64])
// 256 threads/block: 4 nodes x 64 features. W staged in LDS.
__global__ void k_gemm_xw(const float* __restrict__ x, const float* __restrict__ W,
                          float* __restrict__ h, int n) {
    __shared__ float Ws[FDIM * FDIM];
    int t = threadIdx.x;
    #pragma unroll
    for (int i = t; i < FDIM * FDIM; i += 256) Ws[i] = W[i];
    __syncthreads();
    int f     = t & 63;
    int local = t >> 6;                 // 0..3
    int nd    = blockIdx.x * 4 + local;
    if (nd >= n) return;
    const float* xr = x + (size_t)nd * FDIM;
    float acc = 0.0f;
    #pragma unroll
    for (int k = 0; k < FDIM; ++k) acc = fmaf(xr[k], Ws[k * FDIM + f], acc);
    h[(size_t)nd * FDIM + f] = acc;
}

// agg[col] += dinv[row]*dinv[col] * h[row]  — one wave (64 lanes) per edge
__global__ void k_edge_agg(const int* __restrict__ row, const int* __restrict__ col,
                           const float* __restrict__ dinv, const float* __restrict__ h,
                           float* __restrict__ agg, int e) {
    int idx = blockIdx.x * blockDim.x + threadIdx.x;
    int eid = idx >> 6;
    int f   = idx & 63;
    if (eid >= e) return;
    int r = row[eid];
    int c = col[eid];
    float nrm = dinv[r] * dinv[c];
    atomicAdd(&agg[(size_t)c * FDIM + f], nrm * h[(size_t)r * FDIM + f]);
}

// val = relu(agg + dinv^2*h (self loop) + b); pooled[batch] += val; cnt[batch] += 1
__global__ void k_relu_pool(const float* __restrict__ agg, const float* __restrict__ h,
                            const float* __restrict__ dinv, const float* __restrict__ b,
                            const int* __restrict__ batch,
                            float* __restrict__ pooled, float* __restrict__ cnt, int n) {
    int idx = blockIdx.x * blockDim.x + threadIdx.x;
    int nd = idx >> 6;
    int f  = idx & 63;
    if (nd >= n) return;
    float di = dinv[nd];
    float v = agg[(size_t)nd * FDIM + f] + di * di * h[(size_t)nd * FDIM + f] + b[f];
    v = fmaxf(v, 0.0f);
    int g = batch[nd];
    atomicAdd(&pooled[g * FDIM + f], v);
    if (f == 0) atomicAdd(&cnt[g], 1.0f);
}

// out[g][o] = (pooled[g]/cnt[g]) . lin_W[:,o] + lin_b[o]   (128 x 2 = 256 threads)
__global__ void k_final_lin(const float* __restrict__ pooled, const float* __restrict__ cnt,
                            const float* __restrict__ linW, const float* __restrict__ linb,
                            float* __restrict__ out) {
    int t = threadIdx.x;            // 0..255
    int g = t >> 1;
    int o = t & 1;
    float c = fmaxf(cnt[g], 1.0f);
    float acc = 0.0f;
    #pragma unroll
    for (int k = 0; k < FDIM; ++k) acc = fmaf(pooled[g * FDIM + k], linW[k * 2 + o], acc);
    out[g * 2 + o] = acc / c + linb[o];
}

// ---------- launch ----------

extern "C" void kernel_launch(void* const* d_in, const int* in_sizes, int n_in,
                              void* d_out, int out_size, void* d_ws, size_t ws_size,
                              hipStream_t stream) {
    const float* x      = (const float*)d_in[0];   // [N,64]
    const int*   ei     = (const int*)d_in[1];     // [2,E]
    const int*   batch  = (const int*)d_in[2];     // [N]
    const float* W      = (const float*)d_in[3];   // [64,64]
    const float* b      = (const float*)d_in[4];   // [64]
    const float* linW   = (const float*)d_in[5];   // [64,2]
    const float* linb   = (const float*)d_in[6];   // [2]
    float*       out    = (float*)d_out;           // [128,2]

    const int* row = ei;            // edge_index[0] = source
    const int* col = ei + N_EDGES;  // edge_index[1] = target

    // workspace layout (256B-aligned offsets)
    char* ws = (char*)d_ws;
    size_t off = 0;
    float* dinv   = (float*)(ws + off); off += ((size_t)N_NODES * 4 + 255) / 256 * 256;            // 200192
    float* h      = (float*)(ws + off); off += (size_t)N_NODES * FDIM * 4;                          // 12.8MB
    size_t zero_start = off;
    float* agg    = (float*)(ws + off); off += (size_t)N_NODES * FDIM * 4;                          // 12.8MB
    float* pooled = (float*)(ws + off); off += (size_t)NGRAPH * FDIM * 4;                           // 32KB
    float* cnt    = (float*)(ws + off); off += 512;
    size_t zero_bytes = off - zero_start - 512 + (size_t)NGRAPH * 4;  // agg + pooled + cnt(128 floats)

    // zero accumulators every call (graph-capture safe)
    hipMemsetAsync(ws + zero_start, 0, zero_bytes, stream);

    // 1. degree
    k_init_deg<<<(N_NODES + 255) / 256, 256, 0, stream>>>(dinv, N_NODES);
    k_deg_accum<<<(N_EDGES + 255) / 256, 256, 0, stream>>>(col, dinv, N_EDGES);
    k_finish_dinv<<<(N_NODES + 255) / 256, 256, 0, stream>>>(dinv, N_NODES);

    // 2. h = x @ W
    k_gemm_xw<<<(N_NODES + 3) / 4, 256, 0, stream>>>(x, W, h, N_NODES);

    // 3. edge scatter-aggregate
    k_edge_agg<<<(N_EDGES + 3) / 4, 256, 0, stream>>>(row, col, dinv, h, agg, N_EDGES);

    // 4. relu + self-loop term + mean-pool accumulate
    k_relu_pool<<<(N_NODES + 3) / 4, 256, 0, stream>>>(agg, h, dinv, b, batch, pooled, cnt, N_NODES);

    // 5. final linear [128,2]
    k_final_lin<<<1, 256, 0, stream>>>(pooled, cnt, linW, linb, out);
}

// Round 2
// 323.271 us; speedup vs baseline: 1.6472x; 1.6472x over previous
//
#include <hip/hip_runtime.h>

// Problem constants (from reference setup_inputs)
#define N_NODES 50000
#define N_EDGES 800000
#define FDIM    64
#define NGRAPH  128
#define POOL_NODES_PER_BLOCK 512

// ---------- kernels ----------

__global__ void k_init_deg(float* __restrict__ deg, int n) {
    int i = blockIdx.x * blockDim.x + threadIdx.x;
    if (i < n) deg[i] = 1.0f;  // self-loop contributes 1
}

__global__ void k_deg_accum(const int* __restrict__ col, float* __restrict__ deg, int e) {
    int i = blockIdx.x * blockDim.x + threadIdx.x;
    if (i < e) atomicAdd(&deg[col[i]], 1.0f);
}

__global__ void k_finish_dinv(float* __restrict__ deg, int n) {
    int i = blockIdx.x * blockDim.x + threadIdx.x;
    if (i < n) deg[i] = rsqrtf(deg[i]);   // deg >= 1 always (self loop)
}

// h = x @ W   (x: [N,64], W: [64,64], h: [N,64])
// 256 threads/block: 4 nodes x 64 features. W staged in LDS.
__global__ void k_gemm_xw(const float* __restrict__ x, const float* __restrict__ W,
                          float* __restrict__ h, int n) {
    __shared__ float Ws[FDIM * FDIM];
    int t = threadIdx.x;
    #pragma unroll
    for (int i = t; i < FDIM * FDIM; i += 256) Ws[i] = W[i];
    __syncthreads();
    int f     = t & 63;
    int local = t >> 6;                 // 0..3
    int nd    = blockIdx.x * 4 + local;
    if (nd >= n) return;
    const float* xr = x + (size_t)nd * FDIM;
    float acc = 0.0f;
    #pragma unroll
    for (int k = 0; k < FDIM; ++k) acc = fmaf(xr[k], Ws[k * FDIM + f], acc);
    h[(size_t)nd * FDIM + f] = acc;
}

// agg[col] += dinv[row]*dinv[col] * h[row]  — one wave (64 lanes) per edge
__global__ void k_edge_agg(const int* __restrict__ row, const int* __restrict__ col,
                           const float* __restrict__ dinv, const float* __restrict__ h,
                           float* __restrict__ agg, int e) {
    int idx = blockIdx.x * blockDim.x + threadIdx.x;
    int eid = idx >> 6;
    int f   = idx & 63;
    if (eid >= e) return;
    int r = row[eid];
    int c = col[eid];
    float nrm = dinv[r] * dinv[c];
    atomicAdd(&agg[(size_t)c * FDIM + f], nrm * h[(size_t)r * FDIM + f]);
}

// val = relu(agg + dinv^2*h (self loop) + b); pooled[batch] += val (register
// pre-reduction over the sorted batch array → ~2 atomics per thread total)
__global__ void k_relu_pool(const float* __restrict__ agg, const float* __restrict__ h,
                            const float* __restrict__ dinv, const float* __restrict__ b,
                            const int* __restrict__ batch,
                            float* __restrict__ pooled, float* __restrict__ cnt, int n) {
    int f = threadIdx.x & 63;
    int w = threadIdx.x >> 6;            // wave id 0..3
    int start = blockIdx.x * POOL_NODES_PER_BLOCK;
    int end   = min(start + POOL_NODES_PER_BLOCK, n);
    float bf = b[f];
    float acc = 0.0f, cacc = 0.0f;
    int gcur = -1;
    for (int nd = start + w; nd < end; nd += 4) {   // g is wave-uniform each iter
        int g = batch[nd];
        if (g != gcur) {
            if (gcur >= 0) {
                atomicAdd(&pooled[gcur * FDIM + f], acc);
                if (f == 0) atomicAdd(&cnt[gcur], cacc);
            }
            acc = 0.0f; cacc = 0.0f; gcur = g;
        }
        float di = dinv[nd];
        float v = agg[(size_t)nd * FDIM + f] + di * di * h[(size_t)nd * FDIM + f] + bf;
        acc += fmaxf(v, 0.0f);
        cacc += 1.0f;
    }
    if (gcur >= 0) {
        atomicAdd(&pooled[gcur * FDIM + f], acc);
        if (f == 0) atomicAdd(&cnt[gcur], cacc);
    }
}

// out[g][o] = (pooled[g]/cnt[g]) . lin_W[:,o] + lin_b[o]   (128 x 2 = 256 threads)
__global__ void k_final_lin(const float* __restrict__ pooled, const float* __restrict__ cnt,
                            const float* __restrict__ linW, const float* __restrict__ linb,
                            float* __restrict__ out) {
    int t = threadIdx.x;            // 0..255
    int g = t >> 1;
    int o = t & 1;
    float c = fmaxf(cnt[g], 1.0f);
    float acc = 0.0f;
    #pragma unroll
    for (int k = 0; k < FDIM; ++k) acc = fmaf(pooled[g * FDIM + k], linW[k * 2 + o], acc);
    out[g * 2 + o] = acc / c + linb[o];
}

// ---------- launch ----------

extern "C" void kernel_launch(void* const* d_in, const int* in_sizes, int n_in,
                              void* d_out, int out_size, void* d_ws, size_t ws_size,
                              hipStream_t stream) {
    const float* x      = (const float*)d_in[0];   // [N,64]
    const int*   ei     = (const int*)d_in[1];     // [2,E]
    const int*   batch  = (const int*)d_in[2];     // [N]
    const float* W      = (const float*)d_in[3];   // [64,64]
    const float* b      = (const float*)d_in[4];   // [64]
    const float* linW   = (const float*)d_in[5];   // [64,2]
    const float* linb   = (const float*)d_in[6];   // [2]
    float*       out    = (float*)d_out;           // [128,2]

    const int* row = ei;            // edge_index[0] = source
    const int* col = ei + N_EDGES;  // edge_index[1] = target

    // workspace layout (256B-aligned offsets)
    char* ws = (char*)d_ws;
    size_t off = 0;
    float* dinv   = (float*)(ws + off); off += ((size_t)N_NODES * 4 + 255) / 256 * 256;
    float* h      = (float*)(ws + off); off += (size_t)N_NODES * FDIM * 4;                 // 12.8MB
    size_t zero_start = off;
    float* agg    = (float*)(ws + off); off += (size_t)N_NODES * FDIM * 4;                 // 12.8MB
    float* pooled = (float*)(ws + off); off += (size_t)NGRAPH * FDIM * 4;                  // 32KB
    float* cnt    = (float*)(ws + off); off += 512;
    size_t zero_bytes = off - zero_start;

    // zero accumulators every call (graph-capture safe)
    hipMemsetAsync(ws + zero_start, 0, zero_bytes, stream);

    // 1. degree
    k_init_deg<<<(N_NODES + 255) / 256, 256, 0, stream>>>(dinv, N_NODES);
    k_deg_accum<<<(N_EDGES + 255) / 256, 256, 0, stream>>>(col, dinv, N_EDGES);
    k_finish_dinv<<<(N_NODES + 255) / 256, 256, 0, stream>>>(dinv, N_NODES);

    // 2. h = x @ W
    k_gemm_xw<<<(N_NODES + 3) / 4, 256, 0, stream>>>(x, W, h, N_NODES);

    // 3. edge scatter-aggregate
    k_edge_agg<<<(N_EDGES + 3) / 4, 256, 0, stream>>>(row, col, dinv, h, agg, N_EDGES);

    // 4. relu + self-loop term + mean-pool accumulate (register pre-reduction)
    k_relu_pool<<<(N_NODES + POOL_NODES_PER_BLOCK - 1) / POOL_NODES_PER_BLOCK, 256, 0, stream>>>(
        agg, h, dinv, b, batch, pooled, cnt, N_NODES);

    // 5. final linear [128,2]
    k_final_lin<<<1, 256, 0, stream>>>(pooled, cnt, linW, linb, out);
}

// Round 3
// 302.966 us; speedup vs baseline: 1.7576x; 1.0670x over previous
//
#include <hip/hip_runtime.h>

// Problem constants (from reference setup_inputs)
#define N_NODES 50000
#define N_EDGES 800000
#define FDIM    64
#define NGRAPH  128

#define SCAN_THREADS 256
#define SCAN_CHUNK ((N_NODES + SCAN_THREADS - 1) / SCAN_THREADS)   // 196
#define GW 16   // nodes per wave in gather kernel

// ---------- kernels ----------

// integer in-degree histogram (self-loop added later as +1)
__global__ void k_deg_accum(const int* __restrict__ col, int* __restrict__ deg, int e) {
    int i = blockIdx.x * blockDim.x + threadIdx.x;
    if (i < e) atomicAdd(&deg[col[i]], 1);
}

__global__ void k_dinv(const int* __restrict__ deg, float* __restrict__ dinv, int n) {
    int i = blockIdx.x * blockDim.x + threadIdx.x;
    if (i < n) dinv[i] = rsqrtf((float)(deg[i] + 1));   // +1 = self loop
}

// single-block exclusive scan of 50k degrees -> CSR offsets [N+1]
__global__ void k_scan(const int* __restrict__ deg, int* __restrict__ offs) {
    __shared__ int sums[SCAN_THREADS];
    int t = threadIdx.x;
    int start = t * SCAN_CHUNK;
    int end   = min(start + SCAN_CHUNK, N_NODES);
    int s = 0;
    for (int i = start; i < end; ++i) s += deg[i];
    sums[t] = s;
    __syncthreads();
    for (int off = 1; off < SCAN_THREADS; off <<= 1) {
        int v = (t >= off) ? sums[t - off] : 0;
        __syncthreads();
        sums[t] += v;
        __syncthreads();
    }
    int run = (t == 0) ? 0 : sums[t - 1];
    for (int i = start; i < end; ++i) {
        offs[i] = run;
        run += deg[i];
    }
    if (end == N_NODES) offs[N_NODES] = run;   // only t=255 has end==N
}

// scatter each edge's (src, weight=dinv[src]) into its CSR slot
__global__ void k_scatter(const int* __restrict__ row, const int* __restrict__ col,
                          const float* __restrict__ dinv, const int* __restrict__ offs,
                          int* __restrict__ fill, int2* __restrict__ ew, int e) {
    int i = blockIdx.x * blockDim.x + threadIdx.x;
    if (i >= e) return;
    int c = col[i];
    int r = row[i];
    int p = offs[c] + atomicAdd(&fill[c], 1);
    ew[p] = make_int2(r, __float_as_int(dinv[r]));
}

// h = x @ W  (persistent blocks: W staged in LDS once per block)
__global__ void k_gemm_xw(const float* __restrict__ x, const float* __restrict__ W,
                          float* __restrict__ h, int n) {
    __shared__ float Ws[FDIM * FDIM];
    for (int i = threadIdx.x; i < FDIM * FDIM; i += 256) Ws[i] = W[i];
    __syncthreads();
    int f = threadIdx.x & 63;
    int w = threadIdx.x >> 6;
    for (int nd = blockIdx.x * 4 + w; nd < n; nd += gridDim.x * 4) {
        const float* xr = x + (size_t)nd * FDIM;
        float acc = 0.0f;
        #pragma unroll
        for (int k = 0; k < FDIM; ++k) acc = fmaf(xr[k], Ws[k * FDIM + f], acc);
        h[(size_t)nd * FDIM + f] = acc;
    }
}

// fused: CSR gather-aggregate + self-loop + bias + relu + sorted-batch mean-pool
// one wave per GW consecutive nodes, lane = feature
__global__ void k_gather_pool(const int* __restrict__ offs, const int2* __restrict__ ew,
                              const float* __restrict__ h, const float* __restrict__ dinv,
                              const float* __restrict__ b, const int* __restrict__ batch,
                              float* __restrict__ pooled, float* __restrict__ cnt) {
    int f   = threadIdx.x & 63;
    int wid = blockIdx.x * (blockDim.x >> 6) + (threadIdx.x >> 6);
    int start = wid * GW;
    if (start >= N_NODES) return;
    int end = min(start + GW, N_NODES);
    float bf = b[f];
    float pacc = 0.0f, cacc = 0.0f;
    int gcur = batch[start];
    int o0 = offs[start];
    for (int nd = start; nd < end; ++nd) {
        int g = batch[nd];
        if (g != gcur) {
            atomicAdd(&pooled[gcur * FDIM + f], pacc);
            if (f == 0) atomicAdd(&cnt[gcur], cacc);
            pacc = 0.0f; cacc = 0.0f; gcur = g;
        }
        int o1 = offs[nd + 1];
        float acc = 0.0f;
        #pragma unroll 2
        for (int o = o0; o < o1; ++o) {
            int2 e2 = ew[o];                                   // wave-uniform 8B load
            acc = fmaf(__int_as_float(e2.y), h[(size_t)e2.x * FDIM + f], acc);
        }
        float di = dinv[nd];
        float v = fmaf(di, acc, fmaf(di * di, h[(size_t)nd * FDIM + f], bf));
        pacc += fmaxf(v, 0.0f);
        cacc += 1.0f;
        o0 = o1;
    }
    atomicAdd(&pooled[gcur * FDIM + f], pacc);
    if (f == 0) atomicAdd(&cnt[gcur], cacc);
}

// out[g][o] = (pooled[g]/cnt[g]) . lin_W[:,o] + lin_b[o]
__global__ void k_final_lin(const float* __restrict__ pooled, const float* __restrict__ cnt,
                            const float* __restrict__ linW, const float* __restrict__ linb,
                            float* __restrict__ out) {
    int t = threadIdx.x;
    int g = t >> 1;
    int o = t & 1;
    float c = fmaxf(cnt[g], 1.0f);
    float acc = 0.0f;
    #pragma unroll
    for (int k = 0; k < FDIM; ++k) acc = fmaf(pooled[g * FDIM + k], linW[k * 2 + o], acc);
    out[g * 2 + o] = acc / c + linb[o];
}

// ---------- launch ----------

extern "C" void kernel_launch(void* const* d_in, const int* in_sizes, int n_in,
                              void* d_out, int out_size, void* d_ws, size_t ws_size,
                              hipStream_t stream) {
    const float* x      = (const float*)d_in[0];   // [N,64]
    const int*   ei     = (const int*)d_in[1];     // [2,E]
    const int*   batch  = (const int*)d_in[2];     // [N]
    const float* W      = (const float*)d_in[3];   // [64,64]
    const float* b      = (const float*)d_in[4];   // [64]
    const float* linW   = (const float*)d_in[5];   // [64,2]
    const float* linb   = (const float*)d_in[6];   // [2]
    float*       out    = (float*)d_out;           // [128,2]

    const int* row = ei;            // edge_index[0] = source
    const int* col = ei + N_EDGES;  // edge_index[1] = target

    // workspace layout; zeroed region [deg_i|fill|pooled|cnt] is contiguous at front
    char* ws = (char*)d_ws;
    size_t off = 0;
    const size_t NPAD = ((size_t)N_NODES * 4 + 255) / 256 * 256;   // 200192
    int*   deg_i  = (int*)  (ws + off); off += NPAD;
    int*   fill   = (int*)  (ws + off); off += NPAD;
    float* pooled = (float*)(ws + off); off += (size_t)NGRAPH * FDIM * 4;   // 32KB
    float* cnt    = (float*)(ws + off); off += 512;
    size_t zero_bytes = off;
    float* dinv   = (float*)(ws + off); off += NPAD;
    int*   offs   = (int*)  (ws + off); off += NPAD;                         // N+1 ints fit
    int2*  ew     = (int2*) (ws + off); off += (size_t)N_EDGES * 8;          // 6.4MB
    float* h      = (float*)(ws + off); off += (size_t)N_NODES * FDIM * 4;   // 12.8MB

    hipMemsetAsync(ws, 0, zero_bytes, stream);

    // degree + dinv + CSR offsets
    k_deg_accum<<<(N_EDGES + 255) / 256, 256, 0, stream>>>(col, deg_i, N_EDGES);
    k_dinv<<<(N_NODES + 255) / 256, 256, 0, stream>>>(deg_i, dinv, N_NODES);
    k_scan<<<1, SCAN_THREADS, 0, stream>>>(deg_i, offs);

    // h = x @ W
    k_gemm_xw<<<1024, 256, 0, stream>>>(x, W, h, N_NODES);

    // CSR edge scatter (src + weight packed)
    k_scatter<<<(N_EDGES + 255) / 256, 256, 0, stream>>>(row, col, dinv, offs, fill, ew, N_EDGES);

    // fused gather + relu + pool
    int nwaves  = (N_NODES + GW - 1) / GW;
    int nblocks = (nwaves + 3) / 4;
    k_gather_pool<<<nblocks, 256, 0, stream>>>(offs, ew, h, dinv, b, batch, pooled, cnt);

    // final linear [128,2]
    k_final_lin<<<1, 256, 0, stream>>>(pooled, cnt, linW, linb, out);
}